// Round 3
// baseline (150.060 us; speedup 1.0000x reference)
//
#include <hip/hip_runtime.h>

#define SPB 2

// ---- helpers ----
__device__ __forceinline__ float rl(float v, int l) {
    return __builtin_bit_cast(float, __builtin_amdgcn_readlane(__builtin_bit_cast(int, v), l));
}
__device__ __forceinline__ float blo(unsigned d) { return __builtin_bit_cast(float, d << 16); }
__device__ __forceinline__ float bhi(unsigned d) { return __builtin_bit_cast(float, d & 0xffff0000u); }
__device__ __forceinline__ unsigned pack_bf16(float a, float b) {
    unsigned ua = __builtin_bit_cast(unsigned, a);
    unsigned ub = __builtin_bit_cast(unsigned, b);
    ua = (ua + 0x7fffu + ((ua >> 16) & 1u)) >> 16;   // RNE round to bf16
    ub = (ub + 0x7fffu + ((ub >> 16) & 1u)) >> 16;
    return ua | (ub << 16);
}

// ws layout (dword units): [0..191] C factors (3x64 f32), pad to 256,
// [256..8447] W0p (128x64 bf16-pairs), [8448..14591] Whp (3 x 32x64),
// [14592..16639] Wf1p (32x64)
#define WS_C    0
#define WS_W0P  256
#define WS_WHP  (256 + 8192)
#define WS_WF1P (256 + 8192 + 6144)

__global__ __launch_bounds__(256) void preprocess(
    const float* __restrict__ embW1,
    const float* __restrict__ outW0, const float* __restrict__ outWh,
    const float* __restrict__ outWf1, unsigned* __restrict__ ws)
{
    const int g = blockIdx.x * 256 + threadIdx.x;
    if (g < 8192) {                                  // W0p: [k2][f], k2 in [0,128)
        const int k2 = g >> 6, f = g & 63;
        ws[WS_W0P + g] = pack_bf16(outW0[(2*k2)*64 + f], outW0[(2*k2+1)*64 + f]);
    } else if (g < 14336) {                          // Whp: 3 layers of [k2][f], k2 in [0,32)
        const int i = g - 8192;
        const int layer = i >> 11, r = i & 2047;
        const int k2 = r >> 6, f = r & 63;
        const float* W = outWh + layer*4096;
        ws[WS_WHP + i] = pack_bf16(W[(2*k2)*64 + f], W[(2*k2+1)*64 + f]);
    } else if (g < 16384) {                          // Wf1p
        const int i = g - 14336;
        const int k2 = i >> 6, f = i & 63;
        ws[WS_WF1P + i] = pack_bf16(outWf1[(2*k2)*64 + f], outWf1[(2*k2+1)*64 + f]);
    } else if (g < 16576) {                          // C factors: r in [0,3), ch in [0,64)
        const int i = g - 16384;
        const int r = i >> 6, ch = i & 63;
        const float w0 = embW1[ch], w1 = embW1[64 + ch], w2 = embW1[128 + ch];
        float v;
        if (r == 0) {
            v = (1.f + 2.f*__cosf(0.01f*w0)) * (1.f + 2.f*__cosf(0.01f*w1))
              * (1.f + 2.f*__cosf(0.01f*w2)) * (1.f/27.f);
        } else if (r == 1) {
            v = (1.f + 2.f*(__cosf(0.025f*w0) + __cosf(0.05f*w0)))
              * (1.f + 2.f*(__cosf(0.025f*w1) + __cosf(0.05f*w1)))
              * (1.f + 2.f*(__cosf(0.025f*w2) + __cosf(0.05f*w2))) * (1.f/125.f);
        } else {
            v = (1.f + 2.f*(__cosf(0.03f*w0) + __cosf(0.06f*w0) + __cosf(0.09f*w0)))
              * (1.f + 2.f*(__cosf(0.03f*w1) + __cosf(0.06f*w1) + __cosf(0.09f*w1)))
              * (1.f + 2.f*(__cosf(0.03f*w2) + __cosf(0.06f*w2) + __cosf(0.09f*w2))) * (1.f/343.f);
        }
        ((float*)ws)[WS_C + i] = v;
    }
}

__global__ __launch_bounds__(256, 8) void model_fused(
    const float* __restrict__ x, const float* __restrict__ y, const float* __restrict__ t,
    const float* __restrict__ embW1, const float* __restrict__ embb1,
    const float* __restrict__ embwa, const float* __restrict__ embwb,
    const float* __restrict__ embW2, const float* __restrict__ embb2,
    const float* __restrict__ mixW1, const float* __restrict__ mixb1,
    const float* __restrict__ mixwa, const float* __restrict__ mixwb,
    const float* __restrict__ mixW2, const float* __restrict__ mixb2,
    const float* __restrict__ outb0,
    const float* __restrict__ outwa0, const float* __restrict__ outwb0,
    const float* __restrict__ outbh,
    const float* __restrict__ outwah, const float* __restrict__ outwbh,
    const float* __restrict__ outbf1,
    const float* __restrict__ outwaf, const float* __restrict__ outwbf,
    const float* __restrict__ outWf2, const float* __restrict__ outbf2,
    const unsigned* __restrict__ ws,
    float* __restrict__ out, int N)
{
    __shared__ float se[SPB][256];     // mixer output
    __shared__ float pf[2][SPB][64];   // split-k partials
    __shared__ float sh[2][SPB][64];   // head double-buffer

    const int tid  = threadIdx.x;
    const int lane = tid & 63;
    const int n0   = blockIdx.x * SPB;

    // ---- phase 1: per-lane sw and C factors (registers only) ----
    float swv0, swv1, cv1, cv2, cv3;
    {
        const float w0 = embW1[lane], w1 = embW1[64 + lane], w2 = embW1[128 + lane];
        const float bb = embb1[lane];
        const float ewa = embwa[0], ewb = embwb[0];
        const int ns0 = n0;
        const int ns1 = (n0 + 1 < N) ? n0 + 1 : N - 1;
        const float u0 = fmaf(x[ns0], w0, fmaf(y[ns0], w1, fmaf(t[ns0], w2, bb)));
        const float u1 = fmaf(x[ns1], w0, fmaf(y[ns1], w1, fmaf(t[ns1], w2, bb)));
        swv0 = ewa*__sinf(u0) + ewb*__cosf(u0);
        swv1 = ewa*__sinf(u1) + ewb*__cosf(u1);
        const float* C = (const float*)ws + WS_C;
        cv1 = C[lane]; cv2 = C[64 + lane]; cv3 = C[128 + lane];
    }

    // ---- phase 2: 4-region projection via readlane broadcast (zero LDS) ----
    {
        const int c = tid;
        float a00=0.f,a01=0.f,a02=0.f,a03=0.f;
        float a10=0.f,a11=0.f,a12=0.f,a13=0.f;

        #pragma unroll 16
        for (int ch = 0; ch < 64; ++ch) {
            const float w  = embW2[ch*256 + c];          // coalesced dword
            const float s0 = rl(swv0, ch), s1 = rl(swv1, ch);
            const float k1 = rl(cv1, ch), k2 = rl(cv2, ch), k3 = rl(cv3, ch);
            const float t0 = s0 * w, t1 = s1 * w;
            a00 += t0; a01 = fmaf(t0,k1,a01); a02 = fmaf(t0,k2,a02); a03 = fmaf(t0,k3,a03);
            a10 += t1; a11 = fmaf(t1,k1,a11); a12 = fmaf(t1,k2,a12); a13 = fmaf(t1,k3,a13);
        }

        // mixer: params via uniform (scalarized) global loads
        const float mwa = mixwa[0], mwb = mixwb[0], mb2 = mixb2[0];
        const float bb2 = embb2[c];
        {
            const float s0 = a00+bb2, s1 = a01+bb2, s2 = a02+bb2, s3 = a03+bb2;
            float ev = mb2;
            #pragma unroll
            for (int j = 0; j < 8; ++j) {
                float p = fmaf(s0, mixW1[j],
                          fmaf(s1, mixW1[8 + j],
                          fmaf(s2, mixW1[16 + j],
                          fmaf(s3, mixW1[24 + j], mixb1[j]))));
                ev = fmaf(mwa*__sinf(p) + mwb*__cosf(p), mixW2[j], ev);
            }
            se[0][c] = ev;
        }
        {
            const float s0 = a10+bb2, s1 = a11+bb2, s2 = a12+bb2, s3 = a13+bb2;
            float ev = mb2;
            #pragma unroll
            for (int j = 0; j < 8; ++j) {
                float p = fmaf(s0, mixW1[j],
                          fmaf(s1, mixW1[8 + j],
                          fmaf(s2, mixW1[16 + j],
                          fmaf(s3, mixW1[24 + j], mixb1[j]))));
                ev = fmaf(mwa*__sinf(p) + mwb*__cosf(p), mixW2[j], ev);
            }
            se[1][c] = ev;
        }
    }
    __syncthreads();

    // ---- phase 3: head; (h,n,f) = (tid>>7, (tid>>6)&1, tid&63); 2-way split-k ----
    const int h = tid >> 7, n = (tid >> 6) & 1, f = tid & 63;

    // layer 0: 256 -> 64, bf16-pair weights
    {
        const unsigned* W0p = ws + WS_W0P;
        float p = 0.f;
        #pragma unroll 8
        for (int j = h*32; j < h*32 + 32; ++j) {     // acts k = 4j..4j+3
            const float4 a4 = *(const float4*)&se[n][4*j];   // wave-uniform b128
            const unsigned d0 = W0p[(2*j)*64 + f];
            const unsigned d1 = W0p[(2*j+1)*64 + f];
            p = fmaf(a4.x, blo(d0), p); p = fmaf(a4.y, bhi(d0), p);
            p = fmaf(a4.z, blo(d1), p); p = fmaf(a4.w, bhi(d1), p);
        }
        pf[h][n][f] = p;
    }
    __syncthreads();
    if (tid < 128) {
        const float a = pf[0][n][f] + pf[1][n][f] + outb0[f];
        sh[0][n][f] = outwa0[0]*__sinf(a) + outwb0[0]*__cosf(a);
    }
    __syncthreads();

    int cur = 0;
    #pragma unroll
    for (int i = 0; i < 4; ++i) {                    // 3 hidden + f1 (same shape)
        const unsigned* Wp = (i < 3) ? (ws + WS_WHP + i*2048) : (ws + WS_WF1P);
        float p = 0.f;
        #pragma unroll
        for (int j = 0; j < 8; ++j) {                // acts k = 4jj..4jj+3, jj = h*8+j
            const int jj = h*8 + j;
            const float4 a4 = *(const float4*)&sh[cur][n][4*jj];
            const unsigned d0 = Wp[(2*jj)*64 + f];
            const unsigned d1 = Wp[(2*jj+1)*64 + f];
            p = fmaf(a4.x, blo(d0), p); p = fmaf(a4.y, bhi(d0), p);
            p = fmaf(a4.z, blo(d1), p); p = fmaf(a4.w, bhi(d1), p);
        }
        pf[h][n][f] = p;
        __syncthreads();
        if (tid < 128) {
            float a = pf[0][n][f] + pf[1][n][f];
            float wa, wb;
            if (i < 3) { a += outbh[i*64 + f]; wa = outwah[i]; wb = outwbh[i]; }
            else       { a += outbf1[f];       wa = outwaf[0]; wb = outwbf[0]; }
            sh[1 - cur][n][f] = wa*__sinf(a) + wb*__cosf(a);
        }
        __syncthreads();
        cur ^= 1;
    }

    // final: 64 -> 3, fp32 weights
    if (tid < SPB*3) {
        const int nn = tid / 3, o = tid - nn*3;
        float a = outbf2[o];
        #pragma unroll 8
        for (int k = 0; k < 64; ++k)
            a = fmaf(sh[cur][nn][k], outWf2[k*3 + o], a);
        const int gn = n0 + nn;
        if (gn < N) out[gn*3 + o] = a;
    }
}

extern "C" void kernel_launch(void* const* d_in, const int* in_sizes, int n_in,
                              void* d_out, int out_size, void* d_ws, size_t ws_size,
                              hipStream_t stream) {
    const float* x      = (const float*)d_in[0];
    const float* y      = (const float*)d_in[1];
    const float* t      = (const float*)d_in[2];
    const float* embW1  = (const float*)d_in[3];
    const float* embb1  = (const float*)d_in[4];
    const float* embwa  = (const float*)d_in[5];
    const float* embwb  = (const float*)d_in[6];
    const float* embW2  = (const float*)d_in[7];
    const float* embb2  = (const float*)d_in[8];
    const float* mixW1  = (const float*)d_in[9];
    const float* mixb1  = (const float*)d_in[10];
    const float* mixwa  = (const float*)d_in[11];
    const float* mixwb  = (const float*)d_in[12];
    const float* mixW2  = (const float*)d_in[13];
    const float* mixb2  = (const float*)d_in[14];
    const float* outW0  = (const float*)d_in[15];
    const float* outb0  = (const float*)d_in[16];
    const float* outwa0 = (const float*)d_in[17];
    const float* outwb0 = (const float*)d_in[18];
    const float* outWh  = (const float*)d_in[19];
    const float* outbh  = (const float*)d_in[20];
    const float* outwah = (const float*)d_in[21];
    const float* outwbh = (const float*)d_in[22];
    const float* outWf1 = (const float*)d_in[23];
    const float* outbf1 = (const float*)d_in[24];
    const float* outwaf = (const float*)d_in[25];
    const float* outwbf = (const float*)d_in[26];
    const float* outWf2 = (const float*)d_in[27];
    const float* outbf2 = (const float*)d_in[28];
    float* out = (float*)d_out;
    unsigned* ws = (unsigned*)d_ws;

    const int N = in_sizes[0];

    preprocess<<<65, 256, 0, stream>>>(embW1, outW0, outWh, outWf1, ws);

    const int blocks = (N + SPB - 1) / SPB;
    model_fused<<<blocks, 256, 0, stream>>>(
        x, y, t,
        embW1, embb1, embwa, embwb, embW2, embb2,
        mixW1, mixb1, mixwa, mixwb, mixW2, mixb2,
        outb0, outwa0, outwb0,
        outbh, outwah, outwbh,
        outbf1, outwaf, outwbf, outWf2, outbf2,
        ws, out, N);
}

// Round 5
// 143.300 us; speedup vs baseline: 1.0472x; 1.0472x over previous
//
#include <hip/hip_runtime.h>

#define SPB 4

// ---- helpers ----
__device__ __forceinline__ float rl(float v, int l) {
    return __builtin_bit_cast(float, __builtin_amdgcn_readlane(__builtin_bit_cast(int, v), l));
}
__device__ __forceinline__ float blo(unsigned d) { return __builtin_bit_cast(float, d << 16); }
__device__ __forceinline__ float bhi(unsigned d) { return __builtin_bit_cast(float, d & 0xffff0000u); }
__device__ __forceinline__ unsigned pack_bf16(float a, float b) {
    unsigned ua = __builtin_bit_cast(unsigned, a);
    unsigned ub = __builtin_bit_cast(unsigned, b);
    ua = (ua + 0x7fffu + ((ua >> 16) & 1u)) >> 16;   // RNE round to bf16
    ub = (ub + 0x7fffu + ((ub >> 16) & 1u)) >> 16;
    return ua | (ub << 16);
}

// ws layout (dword units): [0..191] C factors (3x64 f32), pad to 256,
// [256..8447] W0p (128x64 bf16-pairs), [8448..14591] Whp (3 x 32x64),
// [14592..16639] Wf1p (32x64)
#define WS_C    0
#define WS_W0P  256
#define WS_WHP  (256 + 8192)
#define WS_WF1P (256 + 8192 + 6144)

__global__ __launch_bounds__(256) void preprocess(
    const float* __restrict__ embW1,
    const float* __restrict__ outW0, const float* __restrict__ outWh,
    const float* __restrict__ outWf1, unsigned* __restrict__ ws)
{
    const int g = blockIdx.x * 256 + threadIdx.x;
    if (g < 8192) {                                  // W0p: [k2][f], k2 in [0,128)
        const int k2 = g >> 6, f = g & 63;
        ws[WS_W0P + g] = pack_bf16(outW0[(2*k2)*64 + f], outW0[(2*k2+1)*64 + f]);
    } else if (g < 14336) {                          // Whp: 3 layers of [k2][f], k2 in [0,32)
        const int i = g - 8192;
        const int layer = i >> 11, r = i & 2047;
        const int k2 = r >> 6, f = r & 63;
        const float* W = outWh + layer*4096;
        ws[WS_WHP + i] = pack_bf16(W[(2*k2)*64 + f], W[(2*k2+1)*64 + f]);
    } else if (g < 16384) {                          // Wf1p
        const int i = g - 14336;
        const int k2 = i >> 6, f = i & 63;
        ws[WS_WF1P + i] = pack_bf16(outWf1[(2*k2)*64 + f], outWf1[(2*k2+1)*64 + f]);
    } else if (g < 16576) {                          // C factors: r in [0,3), ch in [0,64)
        const int i = g - 16384;
        const int r = i >> 6, ch = i & 63;
        const float w0 = embW1[ch], w1 = embW1[64 + ch], w2 = embW1[128 + ch];
        float v;
        if (r == 0) {
            v = (1.f + 2.f*__cosf(0.01f*w0)) * (1.f + 2.f*__cosf(0.01f*w1))
              * (1.f + 2.f*__cosf(0.01f*w2)) * (1.f/27.f);
        } else if (r == 1) {
            v = (1.f + 2.f*(__cosf(0.025f*w0) + __cosf(0.05f*w0)))
              * (1.f + 2.f*(__cosf(0.025f*w1) + __cosf(0.05f*w1)))
              * (1.f + 2.f*(__cosf(0.025f*w2) + __cosf(0.05f*w2))) * (1.f/125.f);
        } else {
            v = (1.f + 2.f*(__cosf(0.03f*w0) + __cosf(0.06f*w0) + __cosf(0.09f*w0)))
              * (1.f + 2.f*(__cosf(0.03f*w1) + __cosf(0.06f*w1) + __cosf(0.09f*w1)))
              * (1.f + 2.f*(__cosf(0.03f*w2) + __cosf(0.06f*w2) + __cosf(0.09f*w2))) * (1.f/343.f);
        }
        ((float*)ws)[WS_C + i] = v;
    }
}

__global__ __launch_bounds__(256, 4) void model_fused(
    const float* __restrict__ x, const float* __restrict__ y, const float* __restrict__ t,
    const float* __restrict__ embW1, const float* __restrict__ embb1,
    const float* __restrict__ embwa, const float* __restrict__ embwb,
    const float* __restrict__ embW2, const float* __restrict__ embb2,
    const float* __restrict__ mixW1, const float* __restrict__ mixb1,
    const float* __restrict__ mixwa, const float* __restrict__ mixwb,
    const float* __restrict__ mixW2, const float* __restrict__ mixb2,
    const float* __restrict__ outb0,
    const float* __restrict__ outwa0, const float* __restrict__ outwb0,
    const float* __restrict__ outbh,
    const float* __restrict__ outwah, const float* __restrict__ outwbh,
    const float* __restrict__ outbf1,
    const float* __restrict__ outwaf, const float* __restrict__ outwbf,
    const float* __restrict__ outWf2, const float* __restrict__ outbf2,
    const unsigned* __restrict__ ws,
    float* __restrict__ out, int N)
{
    __shared__ float se[SPB][256];    // mixer output e per sample
    __shared__ float hfin[SPB][64];   // final hidden for 64->3

    const int tid  = threadIdx.x;
    const int lane = tid & 63;
    const int wv   = tid >> 6;
    const int n0   = blockIdx.x * SPB;

    // ---- phase 1: lane ch computes wave(u) for 4 samples (every wave duplicates) ----
    float swv0, swv1, swv2, swv3;
    {
        const float w0 = embW1[lane], w1 = embW1[64 + lane], w2 = embW1[128 + lane];
        const float bb = embb1[lane];
        const float ewa = embwa[0], ewb = embwb[0];
        const int ns0 = n0;
        const int ns1 = (n0 + 1 < N) ? n0 + 1 : N - 1;
        const int ns2 = (n0 + 2 < N) ? n0 + 2 : N - 1;
        const int ns3 = (n0 + 3 < N) ? n0 + 3 : N - 1;
        const float u0 = fmaf(x[ns0], w0, fmaf(y[ns0], w1, fmaf(t[ns0], w2, bb)));
        const float u1 = fmaf(x[ns1], w0, fmaf(y[ns1], w1, fmaf(t[ns1], w2, bb)));
        const float u2 = fmaf(x[ns2], w0, fmaf(y[ns2], w1, fmaf(t[ns2], w2, bb)));
        const float u3 = fmaf(x[ns3], w0, fmaf(y[ns3], w1, fmaf(t[ns3], w2, bb)));
        swv0 = ewa*__sinf(u0) + ewb*__cosf(u0);
        swv1 = ewa*__sinf(u1) + ewb*__cosf(u1);
        swv2 = ewa*__sinf(u2) + ewb*__cosf(u2);
        swv3 = ewa*__sinf(u3) + ewb*__cosf(u3);
    }

    // ---- phase 2: 4-region projection; C via uniform (SMEM) loads, sw via readlane ----
    {
        const int c = tid;
        const float* Cw = (const float*)ws;   // C[r*64 + ch], uniform addresses
        float acc[4][4];
        #pragma unroll
        for (int s = 0; s < 4; ++s)
            #pragma unroll
            for (int r = 0; r < 4; ++r) acc[s][r] = 0.f;

        #pragma unroll 16
        for (int ch = 0; ch < 64; ++ch) {
            const float w  = embW2[ch*256 + c];          // coalesced, independent loads
            const float k1 = Cw[ch], k2 = Cw[64 + ch], k3 = Cw[128 + ch];  // s_load
            const float s0 = rl(swv0, ch), s1 = rl(swv1, ch);
            const float s2 = rl(swv2, ch), s3 = rl(swv3, ch);
            const float t0 = s0*w, t1 = s1*w, t2 = s2*w, t3 = s3*w;
            acc[0][0] += t0; acc[0][1] = fmaf(t0,k1,acc[0][1]); acc[0][2] = fmaf(t0,k2,acc[0][2]); acc[0][3] = fmaf(t0,k3,acc[0][3]);
            acc[1][0] += t1; acc[1][1] = fmaf(t1,k1,acc[1][1]); acc[1][2] = fmaf(t1,k2,acc[1][2]); acc[1][3] = fmaf(t1,k3,acc[1][3]);
            acc[2][0] += t2; acc[2][1] = fmaf(t2,k1,acc[2][1]); acc[2][2] = fmaf(t2,k2,acc[2][2]); acc[2][3] = fmaf(t2,k3,acc[2][3]);
            acc[3][0] += t3; acc[3][1] = fmaf(t3,k1,acc[3][1]); acc[3][2] = fmaf(t3,k2,acc[3][2]); acc[3][3] = fmaf(t3,k3,acc[3][3]);
        }

        // mixer (params uniform -> scalarized loads)
        const float mwa = mixwa[0], mwb = mixwb[0], mb2 = mixb2[0];
        const float bb2 = embb2[c];
        #pragma unroll
        for (int s = 0; s < 4; ++s) {
            const float f0 = acc[s][0]+bb2, f1 = acc[s][1]+bb2;
            const float f2 = acc[s][2]+bb2, f3 = acc[s][3]+bb2;
            float ev = mb2;
            #pragma unroll
            for (int j = 0; j < 8; ++j) {
                float p = fmaf(f0, mixW1[j],
                          fmaf(f1, mixW1[8 + j],
                          fmaf(f2, mixW1[16 + j],
                          fmaf(f3, mixW1[24 + j], mixb1[j]))));
                ev = fmaf(mwa*__sinf(p) + mwb*__cosf(p), mixW2[j], ev);
            }
            se[s][c] = ev;
        }
    }
    __syncthreads();   // the ONLY block-wide barrier

    // ---- phase 3: wave wv owns sample wv; barrier-free head ----
    const int f = lane, n = wv;
    float h;
    {   // layer 0: 256 -> 64, bf16-pair weights, 4-way ILP accumulators
        const unsigned* W0p = ws + WS_W0P;
        float p0 = 0.f, p1 = 0.f, p2 = 0.f, p3 = 0.f;
        #pragma unroll 16
        for (int j = 0; j < 64; ++j) {               // acts k = 4j..4j+3
            const float4 a4 = *(const float4*)&se[n][4*j];   // wave-uniform broadcast
            const unsigned d0 = W0p[(2*j)*64 + f];
            const unsigned d1 = W0p[(2*j+1)*64 + f];
            p0 = fmaf(a4.x, blo(d0), p0); p1 = fmaf(a4.y, bhi(d0), p1);
            p2 = fmaf(a4.z, blo(d1), p2); p3 = fmaf(a4.w, bhi(d1), p3);
        }
        const float a = (p0 + p1) + (p2 + p3) + outb0[f];
        h = outwa0[0]*__sinf(a) + outwb0[0]*__cosf(a);
    }

    #pragma unroll
    for (int i = 0; i < 4; ++i) {                    // 3 hidden + f1, barrier-free via readlane
        const unsigned* Wp = (i < 3) ? (ws + WS_WHP + i*2048) : (ws + WS_WF1P);
        float p0 = 0.f, p1 = 0.f;
        #pragma unroll
        for (int j = 0; j < 32; ++j) {               // acts k = 2j, 2j+1
            const unsigned d = Wp[j*64 + f];
            const float hk0 = rl(h, 2*j), hk1 = rl(h, 2*j + 1);
            p0 = fmaf(hk0, blo(d), p0);
            p1 = fmaf(hk1, bhi(d), p1);
        }
        float a = p0 + p1;
        float wa, wb;
        if (i < 3) { a += outbh[i*64 + f]; wa = outwah[i]; wb = outwbh[i]; }
        else       { a += outbf1[f];       wa = outwaf[0]; wb = outwbf[0]; }
        h = wa*__sinf(a) + wb*__cosf(a);
    }

    // final 64 -> 3 (wave-local LDS stage; no barrier needed, same wave)
    hfin[n][f] = h;
    if (f < 3) {
        float a = outbf2[f];
        #pragma unroll 16
        for (int k = 0; k < 64; ++k)
            a = fmaf(hfin[n][k], outWf2[k*3 + f], a);
        const int gn = n0 + n;
        if (gn < N) out[gn*3 + f] = a;
    }
}

extern "C" void kernel_launch(void* const* d_in, const int* in_sizes, int n_in,
                              void* d_out, int out_size, void* d_ws, size_t ws_size,
                              hipStream_t stream) {
    const float* x      = (const float*)d_in[0];
    const float* y      = (const float*)d_in[1];
    const float* t      = (const float*)d_in[2];
    const float* embW1  = (const float*)d_in[3];
    const float* embb1  = (const float*)d_in[4];
    const float* embwa  = (const float*)d_in[5];
    const float* embwb  = (const float*)d_in[6];
    const float* embW2  = (const float*)d_in[7];
    const float* embb2  = (const float*)d_in[8];
    const float* mixW1  = (const float*)d_in[9];
    const float* mixb1  = (const float*)d_in[10];
    const float* mixwa  = (const float*)d_in[11];
    const float* mixwb  = (const float*)d_in[12];
    const float* mixW2  = (const float*)d_in[13];
    const float* mixb2  = (const float*)d_in[14];
    const float* outW0  = (const float*)d_in[15];
    const float* outb0  = (const float*)d_in[16];
    const float* outwa0 = (const float*)d_in[17];
    const float* outwb0 = (const float*)d_in[18];
    const float* outWh  = (const float*)d_in[19];
    const float* outbh  = (const float*)d_in[20];
    const float* outwah = (const float*)d_in[21];
    const float* outwbh = (const float*)d_in[22];
    const float* outWf1 = (const float*)d_in[23];
    const float* outbf1 = (const float*)d_in[24];
    const float* outwaf = (const float*)d_in[25];
    const float* outwbf = (const float*)d_in[26];
    const float* outWf2 = (const float*)d_in[27];
    const float* outbf2 = (const float*)d_in[28];
    float* out = (float*)d_out;
    unsigned* ws = (unsigned*)d_ws;

    const int N = in_sizes[0];

    preprocess<<<65, 256, 0, stream>>>(embW1, outW0, outWh, outWf1, ws);

    const int blocks = (N + SPB - 1) / SPB;
    model_fused<<<blocks, 256, 0, stream>>>(
        x, y, t,
        embW1, embb1, embwa, embwb, embW2, embb2,
        mixW1, mixb1, mixwa, mixwb, mixW2, mixb2,
        outb0, outwa0, outwb0,
        outbh, outwah, outwbh,
        outbf1, outwaf, outwbf, outWf2, outbf2,
        ws, out, N);
}